// Round 5
// baseline (381.904 us; speedup 1.0000x reference)
//
#include <hip/hip_runtime.h>
#include <math.h>

#define HH 256
#define WW 256
#define CC 8
#define KK 25
#define ND 9
#define NB 2

__global__ __launch_bounds__(256) void cost_kernel(
    const float* __restrict__ fm,    // [B][C][K][H][W]
    const float* __restrict__ mask,  // [B][K][H][W]
    const float* __restrict__ wgt,   // [C][K]
    float* __restrict__ out)         // [B][C][ND][H][W]
{
#pragma clang fp contract(off)
    const int j = threadIdx.x;            // column (1 px/thread, wave=64 cols)
    int bi = blockIdx.x;
    const int i = bi & 255; bi >>= 8;     // row (uniform per block)
    const int c = bi & 7;  bi >>= 3;      // channel
    const int b = bi;                      // batch

    const float* fmb = fm + (size_t)(b * CC + c) * KK * (HH * WW);
    const float* mb  = mask + (size_t)b * KK * (HH * WW) + i * WW + j;
    const float* wc  = wgt + c * KK;

    // Precompute the 17 possible shifted columns. Entry s holds x = j + (s-8);
    // the tap (k,d) reads shift x = j - dv*d  =>  s = 8 - dv*d  (compile-time).
    // Clamped index (always in-bounds) + validity as exact 1.0/0.0 multiplier.
    int   xc[17];
    float vld[17];
#pragma unroll
    for (int s = 0; s < 17; ++s) {
        const int x = j + (s - 8);
        vld[s] = ((unsigned)x < WW) ? 1.0f : 0.0f;
        xc[s]  = min(max(x, 0), WW - 1);
    }

    float acc[ND];
#pragma unroll
    for (int dd = 0; dd < ND; ++dd) acc[dd] = 0.f;
    float msum = 0.f;

    // Strict numpy order per pixel: k sequential; p=(f*m); t=p*w; acc+=t.
    // Full unroll => shift index is a compile-time constant; y-check uniform.
#pragma unroll
    for (int k = 0; k < KK; ++k) {
        const int du = k / 5 - 2;
        const int dv = k % 5 - 2;
        const float mk = mb[k * (HH * WW)];
        msum = __fadd_rn(msum, mk);
        const float wk = wc[k];
        const float* fpk = fmb + k * (HH * WW);
#pragma unroll
        for (int dd = 0; dd < ND; ++dd) {
            const int d = dd - 4;
            const int y = i - du * d;                    // row shift (ref: i - du*d)
            if (du != 0 && (unsigned)y >= HH) continue;  // uniform: exact skip (+/-0 add)
            const int s = 8 - dv * d;                    // col shift x = j - dv*d
            const float f0 = fpk[y * WW + xc[s]];        // SGPR base + voffset
            const float f  = __fmul_rn(f0, vld[s]);      // exact *1.0, or -> +/-0
            const float p  = __fmul_rn(f, mk);
            const float t  = __fmul_rn(p, wk);
            acc[dd] = __fadd_rn(acc[dd], t);
        }
    }

    const float mavg = __fdiv_rn(msum, 25.0f);
    float* ob = out + (size_t)(b * CC + c) * ND * (HH * WW) + i * WW + j;
#pragma unroll
    for (int dd = 0; dd < ND; ++dd) {
        ob[(size_t)dd * (HH * WW)] = floorf(__fdiv_rn(acc[dd], mavg));
    }
}

extern "C" void kernel_launch(void* const* d_in, const int* in_sizes, int n_in,
                              void* d_out, int out_size, void* d_ws, size_t ws_size,
                              hipStream_t stream) {
    const float* fm   = (const float*)d_in[0];
    const float* mask = (const float*)d_in[1];
    const float* wgt  = (const float*)d_in[2];
    float* out = (float*)d_out;

    dim3 grid(NB * CC * HH);   // 4096 blocks: (b, c, row)
    dim3 block(WW);            // 256 threads: 1 column each
    cost_kernel<<<grid, block, 0, stream>>>(fm, mask, wgt, out);
}

// Round 6
// 350.122 us; speedup vs baseline: 1.0908x; 1.0908x over previous
//
#include <hip/hip_runtime.h>
#include <math.h>

#define HH 256
#define WW 256
#define CC 8
#define KK 25
#define ND 9
#define NB 2
#define HW (HH * WW)
#define WP 272   // 8 zero-pad + 256 + 8 zero-pad (LDS row)

__global__ __launch_bounds__(256) void cost_kernel(
    const float* __restrict__ fm,    // [B][C][K][H][W]
    const float* __restrict__ mask,  // [B][K][H][W]
    const float* __restrict__ wgt,   // [C][K]
    float* __restrict__ out)         // [B][C][ND][H][W]
{
#pragma clang fp contract(off)
    __shared__ float lds[ND][WP];    // 9 x 272 x 4B = 9792 B

    const int j = threadIdx.x;            // column; wave = 64 consecutive cols
    int bi = blockIdx.x;
    const int i = bi & 255; bi >>= 8;     // row (uniform per block)
    const int c = bi & 7;  bi >>= 3;      // channel
    const int b = bi;                      // batch

    const float* fmb = fm + (size_t)(b * CC + c) * KK * HW;      // +k*HW+y*WW+j
    const float* mb  = mask + (size_t)b * KK * HW + i * WW + j;  // +k*HW
    const float* wc  = wgt + c * KK;

    // Zero the column pads once; staging never writes [0..7] / [264..271].
    if (j < ND * 16) {
        const int s = j >> 4, p = j & 15;
        lds[s][p < 8 ? p : 256 + p] = 0.f;
    }

    float acc[ND];
#pragma unroll
    for (int dd = 0; dd < ND; ++dd) acc[dd] = 0.f;
    float msum = 0.f;

    // k = 5*g + v ascending (strict numpy accumulation order).
    // du = g-2 (runtime, row shifts -> uniform SALU), dv = v-2 (static under
    // the 5-way unroll -> every ds_read offset is a compile-time immediate).
    for (int g = 0; g < 5; ++g) {
        const int du = g - 2;
#pragma unroll
        for (int v = 0; v < 5; ++v) {
            const int k = 5 * g + v;
            __syncthreads();   // previous tap's reads done before restaging
            // Stage slot dd <- row (i - du*(dd-4)) of plane k, zero if OOB.
#pragma unroll
            for (int dd = 0; dd < ND; ++dd) {
                const int y = i - du * (dd - 4);   // uniform per slot
                float val = 0.f;
                if ((unsigned)y < HH)
                    val = fmb[(size_t)k * HW + y * WW + j];
                lds[dd][8 + j] = val;
            }
            __syncthreads();
            const float mk = mb[(size_t)k * HW];
            msum = __fadd_rn(msum, mk);
            const float wk = wc[k];
            const int dv = v - 2;
#pragma unroll
            for (int dd = 0; dd < ND; ++dd) {
                const int d = dd - 4;
                const float f = lds[dd][8 + j - dv * d];  // imm-offset ds_read
                const float p = __fmul_rn(f, mk);         // shifted * mask
                const float t = __fmul_rn(p, wk);         // * weight
                acc[dd] = __fadd_rn(acc[dd], t);          // sequential k-sum
            }
        }
    }

    const float mavg = __fdiv_rn(msum, 25.0f);
    float* ob = out + (size_t)(b * CC + c) * ND * HW + i * WW + j;
#pragma unroll
    for (int dd = 0; dd < ND; ++dd)
        ob[(size_t)dd * HW] = floorf(__fdiv_rn(acc[dd], mavg));
}

extern "C" void kernel_launch(void* const* d_in, const int* in_sizes, int n_in,
                              void* d_out, int out_size, void* d_ws, size_t ws_size,
                              hipStream_t stream) {
    const float* fm   = (const float*)d_in[0];
    const float* mask = (const float*)d_in[1];
    const float* wgt  = (const float*)d_in[2];
    float* out = (float*)d_out;

    dim3 grid(NB * CC * HH);   // 4096 blocks: (b, c, row)
    dim3 block(WW);            // 256 threads: 1 column each
    cost_kernel<<<grid, block, 0, stream>>>(fm, mask, wgt, out);
}

// Round 7
// 103.399 us; speedup vs baseline: 3.6935x; 3.3861x over previous
//
#include <hip/hip_runtime.h>
#include <math.h>

#define HH 256
#define WW 256
#define CC 8
#define KK 25
#define ND 9
#define NB 2
#define HW (HH * WW)

__global__ __launch_bounds__(256, 4) void cost_kernel(
    const float* __restrict__ fm,    // [B][C][K][H][W]
    const float* __restrict__ mask,  // [B][K][H][W]
    const float* __restrict__ wgt,   // [C][K]
    float* __restrict__ out)         // [B][C][ND][H][W]
{
#pragma clang fp contract(off)
    const int j = threadIdx.x;            // column; wave = 64 consecutive cols
    int bi = blockIdx.x;
    const int i = bi & 255; bi >>= 8;     // row (uniform per block)
    const int c = bi & 7;  bi >>= 3;      // channel
    const int b = bi;                      // batch

    const float* fmb = fm + (size_t)(b * CC + c) * KK * HW;
    const float* mb  = mask + (size_t)b * KK * HW + i * WW + j;
    const float* wc  = wgt + c * KK;

    float acc[ND];
#pragma unroll
    for (int dd = 0; dd < ND; ++dd) acc[dd] = 0.f;
    float msum = 0.f;

    // k = 5*g + v ascending (strict numpy order). g runtime (du uniform SALU),
    // v + dd unrolled -> dv*d literals. All 45 loads per g-body are branchless
    // and independent -> compiler can batch them for memory-level parallelism.
    for (int g = 0; g < 5; ++g) {
        const int du = g - 2;
#pragma unroll
        for (int v = 0; v < 5; ++v) {
            const int k = 5 * g + v;
            const int dv = v - 2;
            const float mk = mb[k * HW];
            const float wk = wc[k];
            const float* fpk = fmb + (size_t)k * HW;

            float f[ND];     // gathered (and x-masked) taps
            float wv[ND];    // weight with y-validity folded in (uniform)
#pragma unroll
            for (int dd = 0; dd < ND; ++dd) {
                const int d = dd - 4;
                const int y   = i - du * d;              // uniform (SALU)
                const int yok = ((unsigned)y < HH);
                const int yu  = yok ? y : i;             // safe row, result x0
                wv[dd] = yok ? wk : 0.0f;                // t -> +/-0 when y OOB
                const int x  = j - dv * d;               // per-lane, literal shift
                const int xc = min(max(x, 0), WW - 1);   // v_med3_i32
                const float vx = ((unsigned)x < WW) ? 1.0f : 0.0f;
                f[dd] = __fmul_rn(fpk[yu * WW + xc], vx); // *1.0 exact, or +/-0
            }
            msum = __fadd_rn(msum, mk);
#pragma unroll
            for (int dd = 0; dd < ND; ++dd) {
                const float p = __fmul_rn(f[dd], mk);    // shifted * mask
                const float t = __fmul_rn(p, wv[dd]);    // * weight (0 if y OOB)
                acc[dd] = __fadd_rn(acc[dd], t);         // sequential k-sum
            }
        }
    }

    const float mavg = __fdiv_rn(msum, 25.0f);
    float* ob = out + (size_t)(b * CC + c) * ND * HW + i * WW + j;
#pragma unroll
    for (int dd = 0; dd < ND; ++dd)
        ob[(size_t)dd * HW] = floorf(__fdiv_rn(acc[dd], mavg));
}

extern "C" void kernel_launch(void* const* d_in, const int* in_sizes, int n_in,
                              void* d_out, int out_size, void* d_ws, size_t ws_size,
                              hipStream_t stream) {
    const float* fm   = (const float*)d_in[0];
    const float* mask = (const float*)d_in[1];
    const float* wgt  = (const float*)d_in[2];
    float* out = (float*)d_out;

    dim3 grid(NB * CC * HH);   // 4096 blocks: (b, c, row)
    dim3 block(WW);            // 256 threads: 1 column each
    cost_kernel<<<grid, block, 0, stream>>>(fm, mask, wgt, out);
}

// Round 8
// 53.382 us; speedup vs baseline: 7.1542x; 1.9370x over previous
//
#include <hip/hip_runtime.h>
#include <math.h>

#define HH 256
#define WW 256
#define CC 8
#define KK 25
#define ND 9
#define NB 2
#define HW (HH * WW)

typedef int int4v __attribute__((ext_vector_type(4)));

// CK-style raw buffer load: OOB voffset (incl. negative-as-huge) returns 0.
__device__ float llvm_amdgcn_raw_buffer_load_fp32(int4v srsrc, int voffset,
                                                  int soffset, int glc_slc)
    __asm("llvm.amdgcn.raw.buffer.load.f32");

__global__ __launch_bounds__(256) void cost_kernel(
    const float* __restrict__ fm,    // [B][C][K][H][W]
    const float* __restrict__ mask,  // [B][K][H][W]
    const float* __restrict__ wgt,   // [C][K]
    float* __restrict__ out)         // [B][C][ND][H][W]
{
#pragma clang fp contract(off)
    const int j = threadIdx.x;            // column; wave = 64 consecutive cols

    // XCD-chunked swizzle: blockIdx round-robins XCDs (vb%8); give each XCD a
    // contiguous range of processed ids -> its L2 holds one sliding row window.
    const int vb = blockIdx.x;
    const int nid = (vb & 7) * (NB * CC * HH / 8) + (vb >> 3);
    const int i = nid & 255;              // row (uniform)
    const int c = (nid >> 8) & 7;         // channel
    const int b = nid >> 11;              // batch

    const float* fmb = fm + (size_t)(b * CC + c) * KK * HW;
    const float* mb  = mask + (size_t)b * KK * HW + (size_t)i * WW + j;
    const float* wc  = wgt + c * KK;

    // 17 per-lane byte voffsets, x = j + (s-8). Negative x -> huge unsigned
    // voffset -> hardware OOB -> load returns 0 (== numpy zero-pad).
    int voff[17];
#pragma unroll
    for (int s = 0; s < 17; ++s) voff[s] = (j + (s - 8)) * 4;

    float acc[ND];
#pragma unroll
    for (int dd = 0; dd < ND; ++dd) acc[dd] = 0.f;
    float msum = 0.f;

    // k = 5*g + v ascending (strict numpy order). Per tap: 1 buffer_load +
    // 3 FP VALU; all row/validity logic is uniform SALU folded into the SRD.
    for (int g = 0; g < 5; ++g) {
        const int du = g - 2;
#pragma unroll
        for (int v = 0; v < 5; ++v) {
            const int k = 5 * g + v;
            const int dv = v - 2;
            const float mk = mb[(size_t)k * HW];
            const float wk = wc[k];
            const float* fpk = fmb + (size_t)k * HW;
            msum = __fadd_rn(msum, mk);
#pragma unroll
            for (int dd = 0; dd < ND; ++dd) {
                const int d = dd - 4;
                const int y  = i - du * d;                  // uniform
                const int yv = ((unsigned)y < HH);
                const int yc = min(max(y, 0), HH - 1);      // safe row addr
                const float* rowp = fpk + yc * WW;          // uniform -> SGPRs
                int4v srd;
                srd.x = (int)(uintptr_t)rowp;
                srd.y = (int)((uintptr_t)rowp >> 32);
                srd.z = yv ? (WW * 4) : 0;   // num_records: 0 => whole row OOB -> 0
                srd.w = 0x00020000;
                const int s = 8 - dv * d;                   // literal table index
                const float f = llvm_amdgcn_raw_buffer_load_fp32(srd, voff[s], 0, 0);
                const float p = __fmul_rn(f, mk);           // shifted * mask
                const float t = __fmul_rn(p, wk);           // * weight
                acc[dd] = __fadd_rn(acc[dd], t);            // sequential k-sum
            }
        }
    }

    const float mavg = __fdiv_rn(msum, 25.0f);
    float* ob = out + (size_t)(b * CC + c) * ND * HW + (size_t)i * WW + j;
#pragma unroll
    for (int dd = 0; dd < ND; ++dd)
        ob[(size_t)dd * HW] = floorf(__fdiv_rn(acc[dd], mavg));
}

extern "C" void kernel_launch(void* const* d_in, const int* in_sizes, int n_in,
                              void* d_out, int out_size, void* d_ws, size_t ws_size,
                              hipStream_t stream) {
    const float* fm   = (const float*)d_in[0];
    const float* mask = (const float*)d_in[1];
    const float* wgt  = (const float*)d_in[2];
    float* out = (float*)d_out;

    dim3 grid(NB * CC * HH);   // 4096 blocks: (b, c, row), XCD-swizzled in-kernel
    dim3 block(WW);            // 256 threads: 1 column each
    cost_kernel<<<grid, block, 0, stream>>>(fm, mask, wgt, out);
}